// Round 9
// baseline (177.825 us; speedup 1.0000x reference)
//
#include <hip/hip_runtime.h>

typedef unsigned short u16;
typedef unsigned int u32;
typedef float v4f __attribute__((ext_vector_type(4)));
typedef __bf16 bf16x8 __attribute__((ext_vector_type(8)));

#define BATCH 8
#define CDIM 768
#define NHEAD 12
#define DH 64
#define NSEQ 1024
#define SCL 0.18033688011112042f

__device__ __forceinline__ u16 f2bf(float f) {
  u32 u = __builtin_bit_cast(u32, f);
  u += 0x7fffu + ((u >> 16) & 1u);   // RNE
  return (u16)(u >> 16);
}

__device__ __forceinline__ u16 b16(float f) {
  return (u16)((__builtin_bit_cast(u32, f) + 0x8000u) >> 16);
}

__device__ __forceinline__ u32 pkbf(float hi, float lo) {
  u32 a = __builtin_bit_cast(u32, hi) + 0x8000u;
  u32 b = __builtin_bit_cast(u32, lo) + 0x8000u;
  return __builtin_amdgcn_perm(a, b, 0x07060302u);  // {a[31:16], b[31:16]}
}

__device__ __forceinline__ v4f mfma16(bf16x8 a, bf16x8 b, v4f c) {
  return __builtin_amdgcn_mfma_f32_16x16x32_bf16(a, b, c, 0, 0, 0);
}

__device__ __forceinline__ void gload16(const u16* g, u16* l) {
  __builtin_amdgcn_global_load_lds(
      (const __attribute__((address_space(1))) void*)g,
      (__attribute__((address_space(3))) void*)l, 16, 0, 0);
}

#define BARQ asm volatile("s_barrier" ::: "memory")
#define LGKM0 asm volatile("s_waitcnt lgkmcnt(0)" ::: "memory")
#define VMC0 asm volatile("s_waitcnt vmcnt(0)" ::: "memory")
#define FEN asm volatile("" ::: "memory")

// ------------- kernel: fused prep --------------------------------------
__global__ __launch_bounds__(256) void k_prep(const float* __restrict__ x,
                                              const float* __restrict__ wq,
                                              const float* __restrict__ wp,
                                              u16* __restrict__ xT,
                                              u16* __restrict__ wqb,
                                              u16* __restrict__ wpb) {
  __shared__ u16 Ts[64][72];
  int bid = blockIdx.x;
  int t = threadIdx.x;
  if (bid < 2304) {
    bool isQ = bid < 1728;
    const float* s = isQ ? wq : wp;
    u16* d = isQ ? wqb : wpb;
    int i = (isQ ? bid : bid - 1728) * 256 + t;
    float4 v = ((const float4*)s)[i];
    u32 lo = (u32)f2bf(v.x) | ((u32)f2bf(v.y) << 16);
    u32 hi = (u32)f2bf(v.z) | ((u32)f2bf(v.w) << 16);
    ((uint2*)d)[i] = uint2{lo, hi};
    return;
  }
  int id = bid - 2304;
  int p0 = (id & 15) * 64; id >>= 4;
  int c0 = (id % 12) * 64; int b = id / 12;
  int cr = t >> 4;
  int p4 = (t & 15) * 4;
  const float* src = x + ((size_t)b * CDIM + c0) * NSEQ + p0;
#pragma unroll
  for (int i = 0; i < 4; ++i) {
    int c = cr + i * 16;
    float4 v = *(const float4*)&src[(size_t)c * NSEQ + p4];
    Ts[p4 + 0][c] = f2bf(v.x);
    Ts[p4 + 1][c] = f2bf(v.y);
    Ts[p4 + 2][c] = f2bf(v.z);
    Ts[p4 + 3][c] = f2bf(v.w);
  }
  __syncthreads();
  int p = t >> 2;
  int cq = t & 3;
  u16* dst = xT + ((size_t)b * NSEQ + p0 + p) * CDIM + c0;
#pragma unroll
  for (int j = 0; j < 2; ++j) {
    int ch = cq + j * 4;
    *(int4*)&dst[ch * 8] = *(const int4*)&Ts[p][ch * 8];
  }
}

#define NKT 24     // CDIM/32

// ------------- kernel: QKV GEMM, 288x256 tile, 256 blocks (R8 verbatim) -
__global__ __launch_bounds__(512, 2) void k_gemm_qkv(const u16* __restrict__ Wb,
                                                     const u16* __restrict__ xT,
                                                     u16* __restrict__ qkT,
                                                     u16* __restrict__ vbuf) {
  __shared__ u16 sm[3 * 17408];   // 3 bufs x (A 288x32 + B 256x32) = 102 KB
  int bid = blockIdx.x;
  int swz = (bid & 7) * 32 + (bid >> 3);   // bijective: 256 % 8 == 0
  int oIdx = swz % 8, pIdx = swz / 8;      // per XCD: pIdx in [4x,4x+4) = batch x
  int oT = oIdx * 288;
  int pG = pIdx * 256;

  int t = threadIdx.x, lane = t & 63, wid = t >> 6;
  int ln = lane & 15, quad = lane >> 4;
  int wm = wid >> 2, wn = wid & 3;

  int lrow = lane >> 2;
  int scg = ((lane & 3) ^ ((lane >> 3) & 3)) * 8;
  bool roleA = wid < 6;
  int w6 = wid - 6;
  const u16* Asrc = Wb + (size_t)(oT + wid * 48 + lrow) * CDIM + scg;       // roleA
  const u16* Bsrc = xT + (size_t)(pG + (w6 < 0 ? 0 : w6) * 128 + lrow) * CDIM + scg;
  int ldA = wid * 1536;            // u16: rows wid*48 .. +48 within A region
  int ldB = 9216 + (w6 < 0 ? 0 : w6) * 4096;   // B region at 9216

#define STAGEQ(bi, kt) do {                                                \
    u16* bb_ = sm + (bi) * 17408;                                          \
    if (roleA) {                                                           \
      const u16* gp_ = Asrc + (kt) * 32;                                   \
      gload16(gp_, bb_ + ldA);                                             \
      gload16(gp_ + (size_t)16 * CDIM, bb_ + ldA + 512);                   \
      gload16(gp_ + (size_t)32 * CDIM, bb_ + ldA + 1024);                  \
    } else {                                                               \
      const u16* gp_ = Bsrc + (kt) * 32;                                   \
      _Pragma("unroll") for (int i_ = 0; i_ < 8; ++i_)                     \
        gload16(gp_ + (size_t)i_ * 16 * CDIM, bb_ + ldB + i_ * 512);       \
    }                                                                      \
  } while (0)

#define DRAINQ do {                                                        \
    if (roleA) asm volatile("s_waitcnt vmcnt(3)" ::: "memory");            \
    else asm volatile("s_waitcnt vmcnt(8)" ::: "memory");                  \
  } while (0)

  int slot = (quad ^ ((ln >> 1) & 3)) * 8;
  int rAr = (wm * 144 + ln) * 32;
  int rBr = 9216 + (wn * 64 + ln) * 32;

  v4f acc[9][4] = {};

  STAGEQ(0, 0);
  FEN;
  STAGEQ(1, 1);
  DRAINQ;            // tile 0 resident, tile 1 in flight
  BARQ;

  for (int j = 0; j < NKT; ++j) {
    const u16* sb = sm + (j % 3) * 17408;
    int bi2 = (j + 2) % 3;

    // ---- phase A: issue tile j+2; read A m0-4 + B; 20 MFMA ----
    if (j < NKT - 2) STAGEQ(bi2, j + 2);
    bf16x8 af[5], bfr[4];
#pragma unroll
    for (int m = 0; m < 5; ++m)
      af[m] = *(const bf16x8*)&sb[rAr + m * 512 + slot];
#pragma unroll
    for (int n = 0; n < 4; ++n)
      bfr[n] = *(const bf16x8*)&sb[rBr + n * 512 + slot];
    BARQ;
    LGKM0;
    __builtin_amdgcn_sched_barrier(0);
    __builtin_amdgcn_s_setprio(1);
#pragma unroll
    for (int m = 0; m < 5; ++m)
#pragma unroll
      for (int n = 0; n < 4; ++n)
        acc[m][n] = mfma16(af[m], bfr[n], acc[m][n]);
    __builtin_amdgcn_s_setprio(0);
    BARQ;

    // ---- phase B: read A m5-8; counted drain of tile j+1; 16 MFMA ----
    bf16x8 ag[4];
#pragma unroll
    for (int m = 0; m < 4; ++m)
      ag[m] = *(const bf16x8*)&sb[rAr + (m + 5) * 512 + slot];
    if (j < NKT - 2) DRAINQ;
    else if (j == NKT - 2) VMC0;
    BARQ;
    LGKM0;
    __builtin_amdgcn_sched_barrier(0);
    __builtin_amdgcn_s_setprio(1);
#pragma unroll
    for (int m = 0; m < 4; ++m)
#pragma unroll
      for (int n = 0; n < 4; ++n)
        acc[m + 5][n] = mfma16(ag[m], bfr[n], acc[m + 5][n]);
    __builtin_amdgcn_s_setprio(0);
    BARQ;
  }

  // ---- epilogue: ro < 1536 -> qkT (transposed), else -> vbuf ----
#pragma unroll
  for (int m = 0; m < 9; ++m) {
#pragma unroll
    for (int n = 0; n < 4; ++n) {
      int ro = oT + wm * 144 + m * 16 + quad * 4;
      int cp = pG + wn * 64 + n * 16 + ln;
      int b = cp >> 10, p = cp & 1023;
      if (ro < 2 * CDIM) {
        u32 lo = (u32)f2bf(acc[m][n][0]) | ((u32)f2bf(acc[m][n][1]) << 16);
        u32 hi = (u32)f2bf(acc[m][n][2]) | ((u32)f2bf(acc[m][n][3]) << 16);
        *(uint2*)&qkT[((size_t)b * NSEQ + p) * 1536 + ro] = uint2{lo, hi};
      } else {
#pragma unroll
        for (int r = 0; r < 4; ++r)
          vbuf[((size_t)b * CDIM + (ro - 2 * CDIM + r)) * NSEQ + p] =
              f2bf(acc[m][n][r]);
      }
    }
  }
#undef STAGEQ
#undef DRAINQ
}

// ------------- 256x128 3-buf pipelined GEMM core (R4, for proj) ---------
__device__ __forceinline__ void gemm_core(const u16* __restrict__ Ag,
                                          const u16* __restrict__ Bg,
                                          u16* sm, v4f (&acc)[8][4]) {
  int t = threadIdx.x, lane = t & 63, wid = t >> 6;
  int ln = lane & 15, quad = lane >> 4;
  int wm = wid >> 1, wn = wid & 1;

  int srow = wid * 16 + (lane >> 2);
  int scg = ((lane & 3) ^ ((lane >> 3) & 3)) * 8;
  const u16* As0 = Ag + (size_t)srow * CDIM + scg;
  const u16* Bs0 = Bg + (size_t)srow * CDIM + scg;
  int ldw = wid * 512;

  int cA = (quad ^ ((ln >> 1) & 3)) * 8;
  int rA = (wm * 128 + ln) * 32;
  int rB = 8192 + (wn * 64 + ln) * 32;

  {
    u16* sb0 = sm;
    gload16(As0, sb0 + ldw);
    gload16(As0 + (size_t)64 * CDIM, sb0 + 2048 + ldw);
    gload16(As0 + (size_t)128 * CDIM, sb0 + 4096 + ldw);
    gload16(As0 + (size_t)192 * CDIM, sb0 + 6144 + ldw);
    gload16(Bs0, sb0 + 8192 + ldw);
    gload16(Bs0 + (size_t)64 * CDIM, sb0 + 10240 + ldw);
  }
  FEN;
  {
    u16* sb1 = sm + 12288;
    gload16(As0 + 32, sb1 + ldw);
    gload16(As0 + (size_t)64 * CDIM + 32, sb1 + 2048 + ldw);
    gload16(As0 + (size_t)128 * CDIM + 32, sb1 + 4096 + ldw);
    gload16(As0 + (size_t)192 * CDIM + 32, sb1 + 6144 + ldw);
    gload16(Bs0 + 32, sb1 + 8192 + ldw);
    gload16(Bs0 + (size_t)64 * CDIM + 32, sb1 + 10240 + ldw);
  }
  asm volatile("s_waitcnt vmcnt(6)" ::: "memory");
  BARQ;

  for (int kb = 0; kb < 8; ++kb) {
#pragma unroll
    for (int u = 0; u < 3; ++u) {
      int kt = kb * 3 + u;
      const u16* sb = sm + u * 12288;
      u16* nb = sm + ((u + 2) % 3) * 12288;
      int ko = (kt + 2) * 32;

      bf16x8 af[4], bfr[4];
#pragma unroll
      for (int m = 0; m < 4; ++m)
        af[m] = *(const bf16x8*)&sb[rA + m * 512 + cA];
#pragma unroll
      for (int n = 0; n < 4; ++n)
        bfr[n] = *(const bf16x8*)&sb[rB + n * 512 + cA];
      if (kt < NKT - 2) {
        gload16(As0 + ko, nb + ldw);
        gload16(As0 + (size_t)64 * CDIM + ko, nb + 2048 + ldw);
        gload16(Bs0 + ko, nb + 8192 + ldw);
      }
      BARQ;
      LGKM0;
      __builtin_amdgcn_sched_barrier(0);
      __builtin_amdgcn_s_setprio(1);
#pragma unroll
      for (int m = 0; m < 4; ++m)
#pragma unroll
        for (int n = 0; n < 4; ++n)
          acc[m][n] = mfma16(af[m], bfr[n], acc[m][n]);
      __builtin_amdgcn_s_setprio(0);
      BARQ;

#pragma unroll
      for (int m = 0; m < 4; ++m)
        af[m] = *(const bf16x8*)&sb[rA + (m + 4) * 512 + cA];
      if (kt < NKT - 2) {
        gload16(As0 + (size_t)128 * CDIM + ko, nb + 4096 + ldw);
        gload16(As0 + (size_t)192 * CDIM + ko, nb + 6144 + ldw);
        gload16(Bs0 + (size_t)64 * CDIM + ko, nb + 10240 + ldw);
        asm volatile("s_waitcnt vmcnt(6)" ::: "memory");
      } else if (kt == NKT - 2) {
        VMC0;
      }
      BARQ;
      LGKM0;
      __builtin_amdgcn_sched_barrier(0);
      __builtin_amdgcn_s_setprio(1);
#pragma unroll
      for (int m = 0; m < 4; ++m)
#pragma unroll
        for (int n = 0; n < 4; ++n)
          acc[m + 4][n] = mfma16(af[m], bfr[n], acc[m + 4][n]);
      __builtin_amdgcn_s_setprio(0);
      BARQ;
    }
  }
}

// ------------- kernel: flash attention ----------------------------------
// K/V slabs [64][64] with 8-chunk XOR swizzle (R4-proven, conflict-free).
// NEW: Pa pitch-64 XOR-swizzled (was pitch-72: uneven bank distribution =
// the remaining 2.36M conflict cycles). Row pitch 128 B = 32 banks; chunk
// slot c^(row&7); write lands 4 acc/bank (min), read 8/bank (min) — both
// conflict-free by ledger. Same wave writes+reads its own region.
// NEW: setprio(1) around each MFMA cluster (T5; m191 attn +4-7%).
__global__ __launch_bounds__(256) void k_attn(const u16* __restrict__ qkT,
                                              const u16* __restrict__ vbuf,
                                              u16* __restrict__ attnT) {
  int id = blockIdx.x;
  int b = id & 7;
  int j = id >> 3;
  int h = j % 12;
  int nt0 = (j / 12) * 128;

  int t = threadIdx.x, lane = t & 63, wid = t >> 6;
  int ln = lane & 15, quad = lane >> 4;
  int nbase = nt0 + wid * 32;

  __shared__ u16 Ks[2][64 * 64];
  __shared__ u16 Vs[2][64 * 64];
  __shared__ u16 Pa[4][32 * 64];   // [wave][n][m-swizzled], 4 KB/wave
  u16* myP = Pa[wid];

  const u16* qbase = qkT + ((size_t)b * NSEQ + nbase) * 1536 + h * DH;
  bf16x8 aq[2][2];
#pragma unroll
  for (int mt = 0; mt < 2; ++mt)
#pragma unroll
    for (int ks = 0; ks < 2; ++ks)
      aq[mt][ks] = *(const bf16x8*)&qbase[(size_t)(mt * 16 + ln) * 1536 + ks * 32 + quad * 8];

  bf16x8 ones;
#pragma unroll
  for (int i = 0; i < 8; ++i) ones[i] = __builtin_bit_cast(__bf16, (u16)0x3F80);

  v4f oacc[2][4] = {};
  v4f lacc[2] = {};

  int sr8 = lane >> 3;
  int sch = ((lane & 7) ^ sr8) * 8;
  const u16* kg0 = qkT + ((size_t)b * NSEQ + wid * 16 + sr8) * 1536 + CDIM + h * DH + sch;
  const u16* vg0 = vbuf + ((size_t)b * CDIM + h * DH + wid * 16 + sr8) * NSEQ + sch;
  int sK = (wid * 16) * 64;

  int sw0 = (quad ^ (ln & 7)) * 8;
  int sw1 = ((4 + quad) ^ (ln & 7)) * 8;
  // Pa addressing: write chunk (2ct + quad>>1), half (quad&1); read chunk
  // (ks*4+quad). Both slots XOR'd with row&7 == ln&7.
  int e7 = ln & 7;

  gload16(kg0, &Ks[0][sK]);
  gload16(kg0 + (size_t)8 * 1536, &Ks[0][sK + 512]);
  gload16(vg0, &Vs[0][sK]);
  gload16(vg0 + 8 * NSEQ, &Vs[0][sK + 512]);
  __syncthreads();

  for (int s = 0; s < 16; ++s) {
    int cur = s & 1, nxt = cur ^ 1;
    if (s < 15) {
      size_t ko = (size_t)(s + 1) * 64 * 1536;
      int vo = (s + 1) * 64;
      gload16(kg0 + ko, &Ks[nxt][sK]);
      gload16(kg0 + ko + (size_t)8 * 1536, &Ks[nxt][sK + 512]);
      gload16(vg0 + vo, &Vs[nxt][sK]);
      gload16(vg0 + vo + 8 * NSEQ, &Vs[nxt][sK + 512]);
    }

#pragma unroll
    for (int ct = 0; ct < 4; ++ct) {
      bf16x8 kf0 = *(const bf16x8*)&Ks[cur][(ct * 16 + ln) * 64 + sw0];
      bf16x8 kf1 = *(const bf16x8*)&Ks[cur][(ct * 16 + ln) * 64 + sw1];
#pragma unroll
      for (int mt = 0; mt < 2; ++mt) {
        v4f sc = {};
        __builtin_amdgcn_s_setprio(1);
        sc = mfma16(kf0, aq[mt][0], sc);
        sc = mfma16(kf1, aq[mt][1], sc);
        __builtin_amdgcn_s_setprio(0);
        float p0 = __builtin_amdgcn_exp2f(sc[0] * SCL);
        float p1 = __builtin_amdgcn_exp2f(sc[1] * SCL);
        float p2 = __builtin_amdgcn_exp2f(sc[2] * SCL);
        float p3 = __builtin_amdgcn_exp2f(sc[3] * SCL);
        // P[n=mt*16+ln][m=ct*16+quad*4 .. +3]; swizzled slot
        int woff = (mt * 16 + ln) * 64 +
                   (((2 * ct + (quad >> 1)) ^ e7) * 8 + (quad & 1) * 4);
        *(uint2*)&myP[woff] = uint2{pkbf(p1, p0), pkbf(p3, p2)};
      }
    }

    bf16x8 ap[2][2];
#pragma unroll
    for (int mt = 0; mt < 2; ++mt)
#pragma unroll
      for (int ks = 0; ks < 2; ++ks)
        ap[mt][ks] = *(const bf16x8*)&myP[(mt * 16 + ln) * 64 +
                                          ((ks * 4 + quad) ^ e7) * 8];
    __builtin_amdgcn_s_setprio(1);
#pragma unroll
    for (int mt = 0; mt < 2; ++mt) {
      lacc[mt] = mfma16(ap[mt][0], ones, lacc[mt]);
      lacc[mt] = mfma16(ap[mt][1], ones, lacc[mt]);
    }
    __builtin_amdgcn_s_setprio(0);
#pragma unroll
    for (int nt = 0; nt < 4; ++nt) {
      bf16x8 vf0 = *(const bf16x8*)&Vs[cur][(nt * 16 + ln) * 64 + sw0];
      bf16x8 vf1 = *(const bf16x8*)&Vs[cur][(nt * 16 + ln) * 64 + sw1];
      __builtin_amdgcn_s_setprio(1);
#pragma unroll
      for (int mt = 0; mt < 2; ++mt) {
        oacc[mt][nt] = mfma16(ap[mt][0], vf0, oacc[mt][nt]);
        oacc[mt][nt] = mfma16(ap[mt][1], vf1, oacc[mt][nt]);
      }
      __builtin_amdgcn_s_setprio(0);
    }
    __syncthreads();
  }

#pragma unroll
  for (int mt = 0; mt < 2; ++mt) {
#pragma unroll
    for (int r = 0; r < 4; ++r) {
      float inv = 1.0f / lacc[mt][r];
      int n = nbase + mt * 16 + quad * 4 + r;
      u16* dst = attnT + ((size_t)b * NSEQ + n) * CDIM + h * DH;
#pragma unroll
      for (int nt = 0; nt < 4; ++nt)
        dst[nt * 16 + ln] = b16(oacc[mt][nt][r] * inv);
    }
  }
}

// ------------- kernel: proj GEMM (R8 verbatim) --------------------------
__global__ __launch_bounds__(256, 2) void k_gemm_proj(const u16* __restrict__ Wb,
                                                      const u16* __restrict__ aT,
                                                      float* __restrict__ out) {
  __shared__ u16 sm[3 * 12288];   // 72 KB
  int bid = blockIdx.x;
  int swz = (bid & 7) * 24 + (bid >> 3);   // bijective: 192 % 8 == 0
  int oIdx = swz % 3, pIdx = swz / 3;
  int oT = oIdx * 256;
  int pG = pIdx * 128;

  v4f acc[8][4] = {};
  gemm_core(Wb + (size_t)oT * CDIM, aT + (size_t)pG * CDIM, sm, acc);

  int t = threadIdx.x, lane = t & 63, wid = t >> 6;
  int ln = lane & 15, quad = lane >> 4;
  int wm = wid >> 1, wn = wid & 1;
#pragma unroll
  for (int m = 0; m < 8; ++m) {
#pragma unroll
    for (int n = 0; n < 4; ++n) {
      int ro = oT + wm * 128 + m * 16 + quad * 4;
      int cp = pG + wn * 64 + n * 16 + ln;
      int b = cp >> 10, p = cp & 1023;
#pragma unroll
      for (int r = 0; r < 4; ++r)
        out[((size_t)b * CDIM + ro + r) * NSEQ + p] = acc[m][n][r];
    }
  }
}

extern "C" void kernel_launch(void* const* d_in, const int* in_sizes, int n_in,
                              void* d_out, int out_size, void* d_ws, size_t ws_size,
                              hipStream_t stream) {
  const float* x = (const float*)d_in[0];
  const float* w_qkv = (const float*)d_in[1];
  const float* w_proj = (const float*)d_in[2];
  float* out = (float*)d_out;

  char* ws = (char*)d_ws;
  u16* wqkv_bf = (u16*)(ws);
  u16* wproj_bf = (u16*)(ws + 3538944);
  u16* xT = (u16*)(ws + 4718592);
  u16* vbuf = (u16*)(ws + 17301504);
  u16* qkT = (u16*)d_out;
  u16* attnT = xT;

  k_prep<<<dim3(3840), dim3(256), 0, stream>>>(x, w_qkv, w_proj, xT, wqkv_bf, wproj_bf);
  k_gemm_qkv<<<dim3(256), dim3(512), 0, stream>>>(wqkv_bf, xT, qkT, vbuf);
  k_attn<<<dim3(768), dim3(256), 0, stream>>>(qkT, vbuf, attnT);
  k_gemm_proj<<<dim3(192), dim3(256), 0, stream>>>(wproj_bf, attnT, out);
}

// Round 10
// 176.582 us; speedup vs baseline: 1.0070x; 1.0070x over previous
//
#include <hip/hip_runtime.h>

typedef unsigned short u16;
typedef unsigned int u32;
typedef float v4f __attribute__((ext_vector_type(4)));
typedef __bf16 bf16x8 __attribute__((ext_vector_type(8)));

#define BATCH 8
#define CDIM 768
#define NHEAD 12
#define DH 64
#define NSEQ 1024
#define SCL 0.18033688011112042f

__device__ __forceinline__ u16 f2bf(float f) {
  u32 u = __builtin_bit_cast(u32, f);
  u += 0x7fffu + ((u >> 16) & 1u);   // RNE
  return (u16)(u >> 16);
}

__device__ __forceinline__ u16 b16(float f) {
  return (u16)((__builtin_bit_cast(u32, f) + 0x8000u) >> 16);
}

__device__ __forceinline__ u32 pkbf(float hi, float lo) {
  u32 a = __builtin_bit_cast(u32, hi) + 0x8000u;
  u32 b = __builtin_bit_cast(u32, lo) + 0x8000u;
  return __builtin_amdgcn_perm(a, b, 0x07060302u);  // {a[31:16], b[31:16]}
}

__device__ __forceinline__ v4f mfma16(bf16x8 a, bf16x8 b, v4f c) {
  return __builtin_amdgcn_mfma_f32_16x16x32_bf16(a, b, c, 0, 0, 0);
}

__device__ __forceinline__ void gload16(const u16* g, u16* l) {
  __builtin_amdgcn_global_load_lds(
      (const __attribute__((address_space(1))) void*)g,
      (__attribute__((address_space(3))) void*)l, 16, 0, 0);
}

#define BARQ asm volatile("s_barrier" ::: "memory")
#define LGKM0 asm volatile("s_waitcnt lgkmcnt(0)" ::: "memory")
#define VMC0 asm volatile("s_waitcnt vmcnt(0)" ::: "memory")
#define FEN asm volatile("" ::: "memory")

// ------------- kernel: fused prep --------------------------------------
__global__ __launch_bounds__(256) void k_prep(const float* __restrict__ x,
                                              const float* __restrict__ wq,
                                              const float* __restrict__ wp,
                                              u16* __restrict__ xT,
                                              u16* __restrict__ wqb,
                                              u16* __restrict__ wpb) {
  __shared__ u16 Ts[64][72];
  int bid = blockIdx.x;
  int t = threadIdx.x;
  if (bid < 2304) {
    bool isQ = bid < 1728;
    const float* s = isQ ? wq : wp;
    u16* d = isQ ? wqb : wpb;
    int i = (isQ ? bid : bid - 1728) * 256 + t;
    float4 v = ((const float4*)s)[i];
    u32 lo = (u32)f2bf(v.x) | ((u32)f2bf(v.y) << 16);
    u32 hi = (u32)f2bf(v.z) | ((u32)f2bf(v.w) << 16);
    ((uint2*)d)[i] = uint2{lo, hi};
    return;
  }
  int id = bid - 2304;
  int p0 = (id & 15) * 64; id >>= 4;
  int c0 = (id % 12) * 64; int b = id / 12;
  int cr = t >> 4;
  int p4 = (t & 15) * 4;
  const float* src = x + ((size_t)b * CDIM + c0) * NSEQ + p0;
#pragma unroll
  for (int i = 0; i < 4; ++i) {
    int c = cr + i * 16;
    float4 v = *(const float4*)&src[(size_t)c * NSEQ + p4];
    Ts[p4 + 0][c] = f2bf(v.x);
    Ts[p4 + 1][c] = f2bf(v.y);
    Ts[p4 + 2][c] = f2bf(v.z);
    Ts[p4 + 3][c] = f2bf(v.w);
  }
  __syncthreads();
  int p = t >> 2;
  int cq = t & 3;
  u16* dst = xT + ((size_t)b * NSEQ + p0 + p) * CDIM + c0;
#pragma unroll
  for (int j = 0; j < 2; ++j) {
    int ch = cq + j * 4;
    *(int4*)&dst[ch * 8] = *(const int4*)&Ts[p][ch * 8];
  }
}

#define NKT 24     // CDIM/32

// ------------- kernel: QKV GEMM, 288x256 tile, 256 blocks (R8 verbatim) -
__global__ __launch_bounds__(512, 2) void k_gemm_qkv(const u16* __restrict__ Wb,
                                                     const u16* __restrict__ xT,
                                                     u16* __restrict__ qkT,
                                                     u16* __restrict__ vbuf) {
  __shared__ u16 sm[3 * 17408];   // 3 bufs x (A 288x32 + B 256x32) = 102 KB
  int bid = blockIdx.x;
  int swz = (bid & 7) * 32 + (bid >> 3);   // bijective: 256 % 8 == 0
  int oIdx = swz % 8, pIdx = swz / 8;      // per XCD: pIdx in [4x,4x+4) = batch x
  int oT = oIdx * 288;
  int pG = pIdx * 256;

  int t = threadIdx.x, lane = t & 63, wid = t >> 6;
  int ln = lane & 15, quad = lane >> 4;
  int wm = wid >> 2, wn = wid & 3;

  int lrow = lane >> 2;
  int scg = ((lane & 3) ^ ((lane >> 3) & 3)) * 8;
  bool roleA = wid < 6;
  int w6 = wid - 6;
  const u16* Asrc = Wb + (size_t)(oT + wid * 48 + lrow) * CDIM + scg;       // roleA
  const u16* Bsrc = xT + (size_t)(pG + (w6 < 0 ? 0 : w6) * 128 + lrow) * CDIM + scg;
  int ldA = wid * 1536;            // u16: rows wid*48 .. +48 within A region
  int ldB = 9216 + (w6 < 0 ? 0 : w6) * 4096;   // B region at 9216

#define STAGEQ(bi, kt) do {                                                \
    u16* bb_ = sm + (bi) * 17408;                                          \
    if (roleA) {                                                           \
      const u16* gp_ = Asrc + (kt) * 32;                                   \
      gload16(gp_, bb_ + ldA);                                             \
      gload16(gp_ + (size_t)16 * CDIM, bb_ + ldA + 512);                   \
      gload16(gp_ + (size_t)32 * CDIM, bb_ + ldA + 1024);                  \
    } else {                                                               \
      const u16* gp_ = Bsrc + (kt) * 32;                                   \
      _Pragma("unroll") for (int i_ = 0; i_ < 8; ++i_)                     \
        gload16(gp_ + (size_t)i_ * 16 * CDIM, bb_ + ldB + i_ * 512);       \
    }                                                                      \
  } while (0)

#define DRAINQ do {                                                        \
    if (roleA) asm volatile("s_waitcnt vmcnt(3)" ::: "memory");            \
    else asm volatile("s_waitcnt vmcnt(8)" ::: "memory");                  \
  } while (0)

  int slot = (quad ^ ((ln >> 1) & 3)) * 8;
  int rAr = (wm * 144 + ln) * 32;
  int rBr = 9216 + (wn * 64 + ln) * 32;

  v4f acc[9][4] = {};

  STAGEQ(0, 0);
  FEN;
  STAGEQ(1, 1);
  DRAINQ;            // tile 0 resident, tile 1 in flight
  BARQ;

  for (int j = 0; j < NKT; ++j) {
    const u16* sb = sm + (j % 3) * 17408;
    int bi2 = (j + 2) % 3;

    // ---- phase A: issue tile j+2; read A m0-4 + B; 20 MFMA ----
    if (j < NKT - 2) STAGEQ(bi2, j + 2);
    bf16x8 af[5], bfr[4];
#pragma unroll
    for (int m = 0; m < 5; ++m)
      af[m] = *(const bf16x8*)&sb[rAr + m * 512 + slot];
#pragma unroll
    for (int n = 0; n < 4; ++n)
      bfr[n] = *(const bf16x8*)&sb[rBr + n * 512 + slot];
    BARQ;
    LGKM0;
    __builtin_amdgcn_sched_barrier(0);
    __builtin_amdgcn_s_setprio(1);
#pragma unroll
    for (int m = 0; m < 5; ++m)
#pragma unroll
      for (int n = 0; n < 4; ++n)
        acc[m][n] = mfma16(af[m], bfr[n], acc[m][n]);
    __builtin_amdgcn_s_setprio(0);
    BARQ;

    // ---- phase B: read A m5-8; counted drain of tile j+1; 16 MFMA ----
    bf16x8 ag[4];
#pragma unroll
    for (int m = 0; m < 4; ++m)
      ag[m] = *(const bf16x8*)&sb[rAr + (m + 5) * 512 + slot];
    if (j < NKT - 2) DRAINQ;
    else if (j == NKT - 2) VMC0;
    BARQ;
    LGKM0;
    __builtin_amdgcn_sched_barrier(0);
    __builtin_amdgcn_s_setprio(1);
#pragma unroll
    for (int m = 0; m < 4; ++m)
#pragma unroll
      for (int n = 0; n < 4; ++n)
        acc[m + 5][n] = mfma16(ag[m], bfr[n], acc[m + 5][n]);
    __builtin_amdgcn_s_setprio(0);
    BARQ;
  }

  // ---- epilogue: ro < 1536 -> qkT (transposed), else -> vbuf ----
#pragma unroll
  for (int m = 0; m < 9; ++m) {
#pragma unroll
    for (int n = 0; n < 4; ++n) {
      int ro = oT + wm * 144 + m * 16 + quad * 4;
      int cp = pG + wn * 64 + n * 16 + ln;
      int b = cp >> 10, p = cp & 1023;
      if (ro < 2 * CDIM) {
        u32 lo = (u32)f2bf(acc[m][n][0]) | ((u32)f2bf(acc[m][n][1]) << 16);
        u32 hi = (u32)f2bf(acc[m][n][2]) | ((u32)f2bf(acc[m][n][3]) << 16);
        *(uint2*)&qkT[((size_t)b * NSEQ + p) * 1536 + ro] = uint2{lo, hi};
      } else {
#pragma unroll
        for (int r = 0; r < 4; ++r)
          vbuf[((size_t)b * CDIM + (ro - 2 * CDIM + r)) * NSEQ + p] =
              f2bf(acc[m][n][r]);
      }
    }
  }
#undef STAGEQ
#undef DRAINQ
}

// ------------- kernel: flash attention (R9 verbatim) --------------------
__global__ __launch_bounds__(256) void k_attn(const u16* __restrict__ qkT,
                                              const u16* __restrict__ vbuf,
                                              u16* __restrict__ attnT) {
  int id = blockIdx.x;
  int b = id & 7;
  int j = id >> 3;
  int h = j % 12;
  int nt0 = (j / 12) * 128;

  int t = threadIdx.x, lane = t & 63, wid = t >> 6;
  int ln = lane & 15, quad = lane >> 4;
  int nbase = nt0 + wid * 32;

  __shared__ u16 Ks[2][64 * 64];
  __shared__ u16 Vs[2][64 * 64];
  __shared__ u16 Pa[4][32 * 64];   // [wave][n][m-swizzled], 4 KB/wave
  u16* myP = Pa[wid];

  const u16* qbase = qkT + ((size_t)b * NSEQ + nbase) * 1536 + h * DH;
  bf16x8 aq[2][2];
#pragma unroll
  for (int mt = 0; mt < 2; ++mt)
#pragma unroll
    for (int ks = 0; ks < 2; ++ks)
      aq[mt][ks] = *(const bf16x8*)&qbase[(size_t)(mt * 16 + ln) * 1536 + ks * 32 + quad * 8];

  bf16x8 ones;
#pragma unroll
  for (int i = 0; i < 8; ++i) ones[i] = __builtin_bit_cast(__bf16, (u16)0x3F80);

  v4f oacc[2][4] = {};
  v4f lacc[2] = {};

  int sr8 = lane >> 3;
  int sch = ((lane & 7) ^ sr8) * 8;
  const u16* kg0 = qkT + ((size_t)b * NSEQ + wid * 16 + sr8) * 1536 + CDIM + h * DH + sch;
  const u16* vg0 = vbuf + ((size_t)b * CDIM + h * DH + wid * 16 + sr8) * NSEQ + sch;
  int sK = (wid * 16) * 64;

  int sw0 = (quad ^ (ln & 7)) * 8;
  int sw1 = ((4 + quad) ^ (ln & 7)) * 8;
  int e7 = ln & 7;

  gload16(kg0, &Ks[0][sK]);
  gload16(kg0 + (size_t)8 * 1536, &Ks[0][sK + 512]);
  gload16(vg0, &Vs[0][sK]);
  gload16(vg0 + 8 * NSEQ, &Vs[0][sK + 512]);
  __syncthreads();

  for (int s = 0; s < 16; ++s) {
    int cur = s & 1, nxt = cur ^ 1;
    if (s < 15) {
      size_t ko = (size_t)(s + 1) * 64 * 1536;
      int vo = (s + 1) * 64;
      gload16(kg0 + ko, &Ks[nxt][sK]);
      gload16(kg0 + ko + (size_t)8 * 1536, &Ks[nxt][sK + 512]);
      gload16(vg0 + vo, &Vs[nxt][sK]);
      gload16(vg0 + vo + 8 * NSEQ, &Vs[nxt][sK + 512]);
    }

#pragma unroll
    for (int ct = 0; ct < 4; ++ct) {
      bf16x8 kf0 = *(const bf16x8*)&Ks[cur][(ct * 16 + ln) * 64 + sw0];
      bf16x8 kf1 = *(const bf16x8*)&Ks[cur][(ct * 16 + ln) * 64 + sw1];
#pragma unroll
      for (int mt = 0; mt < 2; ++mt) {
        v4f sc = {};
        __builtin_amdgcn_s_setprio(1);
        sc = mfma16(kf0, aq[mt][0], sc);
        sc = mfma16(kf1, aq[mt][1], sc);
        __builtin_amdgcn_s_setprio(0);
        float p0 = __builtin_amdgcn_exp2f(sc[0] * SCL);
        float p1 = __builtin_amdgcn_exp2f(sc[1] * SCL);
        float p2 = __builtin_amdgcn_exp2f(sc[2] * SCL);
        float p3 = __builtin_amdgcn_exp2f(sc[3] * SCL);
        int woff = (mt * 16 + ln) * 64 +
                   (((2 * ct + (quad >> 1)) ^ e7) * 8 + (quad & 1) * 4);
        *(uint2*)&myP[woff] = uint2{pkbf(p1, p0), pkbf(p3, p2)};
      }
    }

    bf16x8 ap[2][2];
#pragma unroll
    for (int mt = 0; mt < 2; ++mt)
#pragma unroll
      for (int ks = 0; ks < 2; ++ks)
        ap[mt][ks] = *(const bf16x8*)&myP[(mt * 16 + ln) * 64 +
                                          ((ks * 4 + quad) ^ e7) * 8];
    __builtin_amdgcn_s_setprio(1);
#pragma unroll
    for (int mt = 0; mt < 2; ++mt) {
      lacc[mt] = mfma16(ap[mt][0], ones, lacc[mt]);
      lacc[mt] = mfma16(ap[mt][1], ones, lacc[mt]);
    }
    __builtin_amdgcn_s_setprio(0);
#pragma unroll
    for (int nt = 0; nt < 4; ++nt) {
      bf16x8 vf0 = *(const bf16x8*)&Vs[cur][(nt * 16 + ln) * 64 + sw0];
      bf16x8 vf1 = *(const bf16x8*)&Vs[cur][(nt * 16 + ln) * 64 + sw1];
      __builtin_amdgcn_s_setprio(1);
#pragma unroll
      for (int mt = 0; mt < 2; ++mt) {
        oacc[mt][nt] = mfma16(ap[mt][0], vf0, oacc[mt][nt]);
        oacc[mt][nt] = mfma16(ap[mt][1], vf1, oacc[mt][nt]);
      }
      __builtin_amdgcn_s_setprio(0);
    }
    __syncthreads();
  }

#pragma unroll
  for (int mt = 0; mt < 2; ++mt) {
#pragma unroll
    for (int r = 0; r < 4; ++r) {
      float inv = 1.0f / lacc[mt][r];
      int n = nbase + mt * 16 + quad * 4 + r;
      u16* dst = attnT + ((size_t)b * NSEQ + n) * CDIM + h * DH;
#pragma unroll
      for (int nt = 0; nt < 4; ++nt)
        dst[nt * 16 + ln] = b16(oacc[mt][nt][r] * inv);
    }
  }
}

// ------------- kernel: proj GEMM, 192x128 tile, 256 blocks (balanced) ---
// R8-qkv template scaled down: 256 thr / 4 waves (2M x 2N), wave-tile
// 96x64 (acc[6][4]), BK=32, 2 phases/tile (12+12 MFMA). 3-buf LDS 60 KB.
// Grid 4 oT x 64 pG = 256 blocks = one balanced round (old proj: 192
// blocks -> 64 CUs idle). Role-split staging: waves 0-2 stage A (4
// gload16/tile), wave 3 stages B (8/tile); tile j+2 issued at top of
// phase A; counted drain vmcnt(4)/vmcnt(8) at mid-phase-B (never 0
// mid-loop). Same chunk-XOR swizzle; k-order unchanged -> bit-identical.
__global__ __launch_bounds__(256, 2) void k_gemm_proj(const u16* __restrict__ Wb,
                                                      const u16* __restrict__ aT,
                                                      float* __restrict__ out) {
  __shared__ u16 sm[3 * 10240];   // 3 x (A 192x32 + B 128x32) = 60 KB
  int bid = blockIdx.x;
  int swz = (bid & 7) * 32 + (bid >> 3);   // bijective: 256 % 8 == 0
  int oIdx = swz % 4, pIdx = swz / 4;      // per XCD: pIdx in [8x,8x+8) = batch x
  int oT = oIdx * 192;
  int pG = pIdx * 128;

  int t = threadIdx.x, lane = t & 63, wid = t >> 6;
  int ln = lane & 15, quad = lane >> 4;
  int wm = wid >> 1, wn = wid & 1;

  int lrow = lane >> 2;
  int scg = ((lane & 3) ^ ((lane >> 3) & 3)) * 8;
  bool roleA = wid < 3;
  const u16* Asrc = Wb + (size_t)(oT + wid * 64 + lrow) * CDIM + scg;   // waves 0-2
  const u16* Bsrc = aT + (size_t)(pG + lrow) * CDIM + scg;              // wave 3
  int ldA = wid * 2048;            // u16: wave's 64 A-rows
  int ldB = 6144;                  // B region at 6144

#define STAGEP(bi, kt) do {                                                \
    u16* bb_ = sm + (bi) * 10240;                                          \
    if (roleA) {                                                           \
      const u16* gp_ = Asrc + (kt) * 32;                                   \
      _Pragma("unroll") for (int i_ = 0; i_ < 4; ++i_)                     \
        gload16(gp_ + (size_t)i_ * 16 * CDIM, bb_ + ldA + i_ * 512);       \
    } else {                                                               \
      const u16* gp_ = Bsrc + (kt) * 32;                                   \
      _Pragma("unroll") for (int i_ = 0; i_ < 8; ++i_)                     \
        gload16(gp_ + (size_t)i_ * 16 * CDIM, bb_ + ldB + i_ * 512);       \
    }                                                                      \
  } while (0)

#define DRAINP do {                                                        \
    if (roleA) asm volatile("s_waitcnt vmcnt(4)" ::: "memory");            \
    else asm volatile("s_waitcnt vmcnt(8)" ::: "memory");                  \
  } while (0)

  int slot = (quad ^ ((ln >> 1) & 3)) * 8;
  int rAr = (wm * 96 + ln) * 32;
  int rBr = 6144 + (wn * 64 + ln) * 32;

  v4f acc[6][4] = {};

  STAGEP(0, 0);
  FEN;
  STAGEP(1, 1);
  DRAINP;            // tile 0 resident, tile 1 in flight
  BARQ;

  for (int j = 0; j < NKT; ++j) {
    const u16* sb = sm + (j % 3) * 10240;
    int bi2 = (j + 2) % 3;

    // ---- phase A: issue tile j+2; read A m0-2 + B; 12 MFMA ----
    if (j < NKT - 2) STAGEP(bi2, j + 2);
    bf16x8 af[3], bfr[4];
#pragma unroll
    for (int m = 0; m < 3; ++m)
      af[m] = *(const bf16x8*)&sb[rAr + m * 512 + slot];
#pragma unroll
    for (int n = 0; n < 4; ++n)
      bfr[n] = *(const bf16x8*)&sb[rBr + n * 512 + slot];
    BARQ;
    LGKM0;
    __builtin_amdgcn_sched_barrier(0);
    __builtin_amdgcn_s_setprio(1);
#pragma unroll
    for (int m = 0; m < 3; ++m)
#pragma unroll
      for (int n = 0; n < 4; ++n)
        acc[m][n] = mfma16(af[m], bfr[n], acc[m][n]);
    __builtin_amdgcn_s_setprio(0);
    BARQ;

    // ---- phase B: read A m3-5; counted drain of tile j+1; 12 MFMA ----
    bf16x8 ag[3];
#pragma unroll
    for (int m = 0; m < 3; ++m)
      ag[m] = *(const bf16x8*)&sb[rAr + (m + 3) * 512 + slot];
    if (j < NKT - 2) DRAINP;
    else if (j == NKT - 2) VMC0;
    BARQ;
    LGKM0;
    __builtin_amdgcn_sched_barrier(0);
    __builtin_amdgcn_s_setprio(1);
#pragma unroll
    for (int m = 0; m < 3; ++m)
#pragma unroll
      for (int n = 0; n < 4; ++n)
        acc[m + 3][n] = mfma16(ag[m], bfr[n], acc[m + 3][n]);
    __builtin_amdgcn_s_setprio(0);
    BARQ;
  }

#pragma unroll
  for (int m = 0; m < 6; ++m) {
#pragma unroll
    for (int n = 0; n < 4; ++n) {
      int ro = oT + wm * 96 + m * 16 + quad * 4;
      int cp = pG + wn * 64 + n * 16 + ln;
      int b = cp >> 10, p = cp & 1023;
#pragma unroll
      for (int r = 0; r < 4; ++r)
        out[((size_t)b * CDIM + ro + r) * NSEQ + p] = acc[m][n][r];
    }
  }
#undef STAGEP
#undef DRAINP
}

extern "C" void kernel_launch(void* const* d_in, const int* in_sizes, int n_in,
                              void* d_out, int out_size, void* d_ws, size_t ws_size,
                              hipStream_t stream) {
  const float* x = (const float*)d_in[0];
  const float* w_qkv = (const float*)d_in[1];
  const float* w_proj = (const float*)d_in[2];
  float* out = (float*)d_out;

  char* ws = (char*)d_ws;
  u16* wqkv_bf = (u16*)(ws);
  u16* wproj_bf = (u16*)(ws + 3538944);
  u16* xT = (u16*)(ws + 4718592);
  u16* vbuf = (u16*)(ws + 17301504);
  u16* qkT = (u16*)d_out;
  u16* attnT = xT;

  k_prep<<<dim3(3840), dim3(256), 0, stream>>>(x, w_qkv, w_proj, xT, wqkv_bf, wproj_bf);
  k_gemm_qkv<<<dim3(256), dim3(512), 0, stream>>>(wqkv_bf, xT, qkT, vbuf);
  k_attn<<<dim3(768), dim3(256), 0, stream>>>(qkT, vbuf, attnT);
  k_gemm_proj<<<dim3(256), dim3(256), 0, stream>>>(wproj_bf, attnT, out);
}

// Round 11
// 172.442 us; speedup vs baseline: 1.0312x; 1.0240x over previous
//
#include <hip/hip_runtime.h>

typedef unsigned short u16;
typedef unsigned int u32;
typedef float v4f __attribute__((ext_vector_type(4)));
typedef __bf16 bf16x8 __attribute__((ext_vector_type(8)));

#define BATCH 8
#define CDIM 768
#define NHEAD 12
#define DH 64
#define NSEQ 1024
#define SCL 0.18033688011112042f

__device__ __forceinline__ u16 f2bf(float f) {
  u32 u = __builtin_bit_cast(u32, f);
  u += 0x7fffu + ((u >> 16) & 1u);   // RNE
  return (u16)(u >> 16);
}

__device__ __forceinline__ u16 b16(float f) {
  return (u16)((__builtin_bit_cast(u32, f) + 0x8000u) >> 16);
}

__device__ __forceinline__ u32 pkbf(float hi, float lo) {
  u32 a = __builtin_bit_cast(u32, hi) + 0x8000u;
  u32 b = __builtin_bit_cast(u32, lo) + 0x8000u;
  return __builtin_amdgcn_perm(a, b, 0x07060302u);  // {a[31:16], b[31:16]}
}

__device__ __forceinline__ v4f mfma16(bf16x8 a, bf16x8 b, v4f c) {
  return __builtin_amdgcn_mfma_f32_16x16x32_bf16(a, b, c, 0, 0, 0);
}

__device__ __forceinline__ void gload16(const u16* g, u16* l) {
  __builtin_amdgcn_global_load_lds(
      (const __attribute__((address_space(1))) void*)g,
      (__attribute__((address_space(3))) void*)l, 16, 0, 0);
}

#define BARQ asm volatile("s_barrier" ::: "memory")
#define LGKM0 asm volatile("s_waitcnt lgkmcnt(0)" ::: "memory")
#define VMC0 asm volatile("s_waitcnt vmcnt(0)" ::: "memory")
#define FEN asm volatile("" ::: "memory")

// ------------- kernel: fused prep --------------------------------------
__global__ __launch_bounds__(256) void k_prep(const float* __restrict__ x,
                                              const float* __restrict__ wq,
                                              const float* __restrict__ wp,
                                              u16* __restrict__ xT,
                                              u16* __restrict__ wqb,
                                              u16* __restrict__ wpb) {
  __shared__ u16 Ts[64][72];
  int bid = blockIdx.x;
  int t = threadIdx.x;
  if (bid < 2304) {
    bool isQ = bid < 1728;
    const float* s = isQ ? wq : wp;
    u16* d = isQ ? wqb : wpb;
    int i = (isQ ? bid : bid - 1728) * 256 + t;
    float4 v = ((const float4*)s)[i];
    u32 lo = (u32)f2bf(v.x) | ((u32)f2bf(v.y) << 16);
    u32 hi = (u32)f2bf(v.z) | ((u32)f2bf(v.w) << 16);
    ((uint2*)d)[i] = uint2{lo, hi};
    return;
  }
  int id = bid - 2304;
  int p0 = (id & 15) * 64; id >>= 4;
  int c0 = (id % 12) * 64; int b = id / 12;
  int cr = t >> 4;
  int p4 = (t & 15) * 4;
  const float* src = x + ((size_t)b * CDIM + c0) * NSEQ + p0;
#pragma unroll
  for (int i = 0; i < 4; ++i) {
    int c = cr + i * 16;
    float4 v = *(const float4*)&src[(size_t)c * NSEQ + p4];
    Ts[p4 + 0][c] = f2bf(v.x);
    Ts[p4 + 1][c] = f2bf(v.y);
    Ts[p4 + 2][c] = f2bf(v.z);
    Ts[p4 + 3][c] = f2bf(v.w);
  }
  __syncthreads();
  int p = t >> 2;
  int cq = t & 3;
  u16* dst = xT + ((size_t)b * NSEQ + p0 + p) * CDIM + c0;
#pragma unroll
  for (int j = 0; j < 2; ++j) {
    int ch = cq + j * 4;
    *(int4*)&dst[ch * 8] = *(const int4*)&Ts[p][ch * 8];
  }
}

#define NKT 24     // CDIM/32

// ------------- kernel: QKV GEMM, 288x256 tile, 256 blocks (R8 verbatim) -
__global__ __launch_bounds__(512, 2) void k_gemm_qkv(const u16* __restrict__ Wb,
                                                     const u16* __restrict__ xT,
                                                     u16* __restrict__ qkT,
                                                     u16* __restrict__ vbuf) {
  __shared__ u16 sm[3 * 17408];   // 3 bufs x (A 288x32 + B 256x32) = 102 KB
  int bid = blockIdx.x;
  int swz = (bid & 7) * 32 + (bid >> 3);   // bijective: 256 % 8 == 0
  int oIdx = swz % 8, pIdx = swz / 8;      // per XCD: pIdx in [4x,4x+4) = batch x
  int oT = oIdx * 288;
  int pG = pIdx * 256;

  int t = threadIdx.x, lane = t & 63, wid = t >> 6;
  int ln = lane & 15, quad = lane >> 4;
  int wm = wid >> 2, wn = wid & 3;

  int lrow = lane >> 2;
  int scg = ((lane & 3) ^ ((lane >> 3) & 3)) * 8;
  bool roleA = wid < 6;
  int w6 = wid - 6;
  const u16* Asrc = Wb + (size_t)(oT + wid * 48 + lrow) * CDIM + scg;       // roleA
  const u16* Bsrc = xT + (size_t)(pG + (w6 < 0 ? 0 : w6) * 128 + lrow) * CDIM + scg;
  int ldA = wid * 1536;            // u16: rows wid*48 .. +48 within A region
  int ldB = 9216 + (w6 < 0 ? 0 : w6) * 4096;   // B region at 9216

#define STAGEQ(bi, kt) do {                                                \
    u16* bb_ = sm + (bi) * 17408;                                          \
    if (roleA) {                                                           \
      const u16* gp_ = Asrc + (kt) * 32;                                   \
      gload16(gp_, bb_ + ldA);                                             \
      gload16(gp_ + (size_t)16 * CDIM, bb_ + ldA + 512);                   \
      gload16(gp_ + (size_t)32 * CDIM, bb_ + ldA + 1024);                  \
    } else {                                                               \
      const u16* gp_ = Bsrc + (kt) * 32;                                   \
      _Pragma("unroll") for (int i_ = 0; i_ < 8; ++i_)                     \
        gload16(gp_ + (size_t)i_ * 16 * CDIM, bb_ + ldB + i_ * 512);       \
    }                                                                      \
  } while (0)

#define DRAINQ do {                                                        \
    if (roleA) asm volatile("s_waitcnt vmcnt(3)" ::: "memory");            \
    else asm volatile("s_waitcnt vmcnt(8)" ::: "memory");                  \
  } while (0)

  int slot = (quad ^ ((ln >> 1) & 3)) * 8;
  int rAr = (wm * 144 + ln) * 32;
  int rBr = 9216 + (wn * 64 + ln) * 32;

  v4f acc[9][4] = {};

  STAGEQ(0, 0);
  FEN;
  STAGEQ(1, 1);
  DRAINQ;            // tile 0 resident, tile 1 in flight
  BARQ;

  for (int j = 0; j < NKT; ++j) {
    const u16* sb = sm + (j % 3) * 17408;
    int bi2 = (j + 2) % 3;

    // ---- phase A: issue tile j+2; read A m0-4 + B; 20 MFMA ----
    if (j < NKT - 2) STAGEQ(bi2, j + 2);
    bf16x8 af[5], bfr[4];
#pragma unroll
    for (int m = 0; m < 5; ++m)
      af[m] = *(const bf16x8*)&sb[rAr + m * 512 + slot];
#pragma unroll
    for (int n = 0; n < 4; ++n)
      bfr[n] = *(const bf16x8*)&sb[rBr + n * 512 + slot];
    BARQ;
    LGKM0;
    __builtin_amdgcn_sched_barrier(0);
    __builtin_amdgcn_s_setprio(1);
#pragma unroll
    for (int m = 0; m < 5; ++m)
#pragma unroll
      for (int n = 0; n < 4; ++n)
        acc[m][n] = mfma16(af[m], bfr[n], acc[m][n]);
    __builtin_amdgcn_s_setprio(0);
    BARQ;

    // ---- phase B: read A m5-8; counted drain of tile j+1; 16 MFMA ----
    bf16x8 ag[4];
#pragma unroll
    for (int m = 0; m < 4; ++m)
      ag[m] = *(const bf16x8*)&sb[rAr + (m + 5) * 512 + slot];
    if (j < NKT - 2) DRAINQ;
    else if (j == NKT - 2) VMC0;
    BARQ;
    LGKM0;
    __builtin_amdgcn_sched_barrier(0);
    __builtin_amdgcn_s_setprio(1);
#pragma unroll
    for (int m = 0; m < 4; ++m)
#pragma unroll
      for (int n = 0; n < 4; ++n)
        acc[m + 5][n] = mfma16(ag[m], bfr[n], acc[m + 5][n]);
    __builtin_amdgcn_s_setprio(0);
    BARQ;
  }

  // ---- epilogue: ro < 1536 -> qkT (transposed), else -> vbuf ----
#pragma unroll
  for (int m = 0; m < 9; ++m) {
#pragma unroll
    for (int n = 0; n < 4; ++n) {
      int ro = oT + wm * 144 + m * 16 + quad * 4;
      int cp = pG + wn * 64 + n * 16 + ln;
      int b = cp >> 10, p = cp & 1023;
      if (ro < 2 * CDIM) {
        u32 lo = (u32)f2bf(acc[m][n][0]) | ((u32)f2bf(acc[m][n][1]) << 16);
        u32 hi = (u32)f2bf(acc[m][n][2]) | ((u32)f2bf(acc[m][n][3]) << 16);
        *(uint2*)&qkT[((size_t)b * NSEQ + p) * 1536 + ro] = uint2{lo, hi};
      } else {
#pragma unroll
        for (int r = 0; r < 4; ++r)
          vbuf[((size_t)b * CDIM + (ro - 2 * CDIM + r)) * NSEQ + p] =
              f2bf(acc[m][n][r]);
      }
    }
  }
#undef STAGEQ
#undef DRAINQ
}

// ------------- kernel: flash attention (T15 pipelined) ------------------
// Same ops/layouts as R10 (K/V 8-chunk XOR swizzle; Pa pitch-64 swizzle),
// but software-pipelined within the wave: iteration s computes QK+exp+
// P-store for slab s+1 and PV for slab s with ap read last iteration.
// PV MFMAs no longer depend on this iteration's exp -> exp VALU overlaps
// PV MFMA; the P-store->ap-read gap is filled by 20 MFMAs, not a stall.
// K staged 1 phase ahead (dbuf (s)&1 write never overlaps (s+1)&1 read);
// V 1 phase ahead; one __syncthreads per half-iteration (same count).
// Manual 2-unroll with named apA/apB (rule #20: no runtime-indexed frags).
__global__ __launch_bounds__(256) void k_attn(const u16* __restrict__ qkT,
                                              const u16* __restrict__ vbuf,
                                              u16* __restrict__ attnT) {
  int id = blockIdx.x;
  int b = id & 7;
  int j = id >> 3;
  int h = j % 12;
  int nt0 = (j / 12) * 128;

  int t = threadIdx.x, lane = t & 63, wid = t >> 6;
  int ln = lane & 15, quad = lane >> 4;
  int nbase = nt0 + wid * 32;

  __shared__ u16 Ks[2][64 * 64];
  __shared__ u16 Vs[2][64 * 64];
  __shared__ u16 Pa[4][32 * 64];   // [wave][n][m-swizzled], 4 KB/wave
  u16* myP = Pa[wid];

  const u16* qbase = qkT + ((size_t)b * NSEQ + nbase) * 1536 + h * DH;
  bf16x8 aq[2][2];
#pragma unroll
  for (int mt = 0; mt < 2; ++mt)
#pragma unroll
    for (int ks = 0; ks < 2; ++ks)
      aq[mt][ks] = *(const bf16x8*)&qbase[(size_t)(mt * 16 + ln) * 1536 + ks * 32 + quad * 8];

  bf16x8 ones;
#pragma unroll
  for (int i = 0; i < 8; ++i) ones[i] = __builtin_bit_cast(__bf16, (u16)0x3F80);

  v4f oacc[2][4] = {};
  v4f lacc[2] = {};

  int sr8 = lane >> 3;
  int sch = ((lane & 7) ^ sr8) * 8;
  const u16* kg0 = qkT + ((size_t)b * NSEQ + wid * 16 + sr8) * 1536 + CDIM + h * DH + sch;
  const u16* vg0 = vbuf + ((size_t)b * CDIM + h * DH + wid * 16 + sr8) * NSEQ + sch;
  int sK = wid * 1024;   // wave's 16-row LDS slab base (u16)

  int sw0 = (quad ^ (ln & 7)) * 8;
  int sw1 = ((4 + quad) ^ (ln & 7)) * 8;
  int e7 = ln & 7;

#define STAGEK(kb, s_) do { size_t ko_ = (size_t)(s_) * 64 * 1536;          \
    gload16(kg0 + ko_, &Ks[kb][sK]);                                        \
    gload16(kg0 + ko_ + (size_t)8 * 1536, &Ks[kb][sK + 512]); } while (0)
#define STAGEV(vb, s_) do { int vo_ = (s_) * 64;                            \
    gload16(vg0 + vo_, &Vs[vb][sK]);                                        \
    gload16(vg0 + vo_ + 8 * NSEQ, &Vs[vb][sK + 512]); } while (0)

#define QKEXP(kb) do {                                                      \
    _Pragma("unroll") for (int ct = 0; ct < 4; ++ct) {                      \
      bf16x8 kf0 = *(const bf16x8*)&Ks[kb][(ct * 16 + ln) * 64 + sw0];      \
      bf16x8 kf1 = *(const bf16x8*)&Ks[kb][(ct * 16 + ln) * 64 + sw1];      \
      _Pragma("unroll") for (int mt = 0; mt < 2; ++mt) {                    \
        v4f sc = {};                                                        \
        sc = mfma16(kf0, aq[mt][0], sc);                                    \
        sc = mfma16(kf1, aq[mt][1], sc);                                    \
        float p0 = __builtin_amdgcn_exp2f(sc[0] * SCL);                     \
        float p1 = __builtin_amdgcn_exp2f(sc[1] * SCL);                     \
        float p2 = __builtin_amdgcn_exp2f(sc[2] * SCL);                     \
        float p3 = __builtin_amdgcn_exp2f(sc[3] * SCL);                     \
        int woff = (mt * 16 + ln) * 64 +                                    \
                   (((2 * ct + (quad >> 1)) ^ e7) * 8 + (quad & 1) * 4);    \
        *(uint2*)&myP[woff] = uint2{pkbf(p1, p0), pkbf(p3, p2)};            \
      }                                                                     \
    }                                                                       \
  } while (0)

#define READAP(ap) do {                                                     \
    _Pragma("unroll") for (int mt = 0; mt < 2; ++mt)                        \
      _Pragma("unroll") for (int ks = 0; ks < 2; ++ks)                      \
        ap[mt][ks] = *(const bf16x8*)&myP[(mt * 16 + ln) * 64 +             \
                                          ((ks * 4 + quad) ^ e7) * 8];      \
  } while (0)

#define PVSTEP(vb, ap) do {                                                 \
    __builtin_amdgcn_s_setprio(1);                                          \
    _Pragma("unroll") for (int mt = 0; mt < 2; ++mt) {                      \
      lacc[mt] = mfma16(ap[mt][0], ones, lacc[mt]);                         \
      lacc[mt] = mfma16(ap[mt][1], ones, lacc[mt]);                         \
    }                                                                       \
    __builtin_amdgcn_s_setprio(0);                                          \
    _Pragma("unroll") for (int nt = 0; nt < 4; ++nt) {                      \
      bf16x8 vf0 = *(const bf16x8*)&Vs[vb][(nt * 16 + ln) * 64 + sw0];      \
      bf16x8 vf1 = *(const bf16x8*)&Vs[vb][(nt * 16 + ln) * 64 + sw1];      \
      __builtin_amdgcn_s_setprio(1);                                        \
      _Pragma("unroll") for (int mt = 0; mt < 2; ++mt) {                    \
        oacc[mt][nt] = mfma16(ap[mt][0], vf0, oacc[mt][nt]);                \
        oacc[mt][nt] = mfma16(ap[mt][1], vf1, oacc[mt][nt]);                \
      }                                                                     \
      __builtin_amdgcn_s_setprio(0);                                        \
    }                                                                       \
  } while (0)

  bf16x8 apA[2][2], apB[2][2];

  // ---- prologue: slab 0 resident; P(0) computed; K(1) in flight ----
  STAGEK(0, 0);
  STAGEV(0, 0);
  __syncthreads();
  QKEXP(0);
  STAGEK(1, 1);
  READAP(apA);

#pragma unroll 1
  for (int s = 0; s < 16; s += 2) {
    // ---- even half: QK(s+1) | PV(s) ----
    __syncthreads();                       // drains K(s+1), V(s)
    if (s < 14) STAGEK(0, s + 2);          // Kbuf0: K(s) dead
    STAGEV(1, s + 1);                      // Vbuf1: V(s-1) dead
    QKEXP(1);                              // K(s+1) from Kbuf1
    PVSTEP(0, apA);                        // V(s) from Vbuf0, P(s)
    READAP(apB);                           // P(s+1), gap filled by PV
    // ---- odd half: QK(s+2) | PV(s+1) ----
    __syncthreads();                       // drains K(s+2), V(s+1)
    if (s < 13) STAGEK(1, s + 3);          // Kbuf1: K(s+1) dead
    if (s < 14) {
      STAGEV(0, s + 2);                    // Vbuf0: V(s) dead
      QKEXP(0);                            // K(s+2) from Kbuf0
    }
    PVSTEP(1, apB);                        // V(s+1) from Vbuf1, P(s+1)
    if (s < 14) READAP(apA);               // P(s+2)
  }

#undef STAGEK
#undef STAGEV
#undef QKEXP
#undef READAP
#undef PVSTEP

#pragma unroll
  for (int mt = 0; mt < 2; ++mt) {
#pragma unroll
    for (int r = 0; r < 4; ++r) {
      float inv = 1.0f / lacc[mt][r];
      int n = nbase + mt * 16 + quad * 4 + r;
      u16* dst = attnT + ((size_t)b * NSEQ + n) * CDIM + h * DH;
#pragma unroll
      for (int nt = 0; nt < 4; ++nt)
        dst[nt * 16 + ln] = b16(oacc[mt][nt][r] * inv);
    }
  }
}

// ------------- kernel: proj GEMM, 192x128 tile, 256 blocks (R10 verbatim)
__global__ __launch_bounds__(256, 2) void k_gemm_proj(const u16* __restrict__ Wb,
                                                      const u16* __restrict__ aT,
                                                      float* __restrict__ out) {
  __shared__ u16 sm[3 * 10240];   // 3 x (A 192x32 + B 128x32) = 60 KB
  int bid = blockIdx.x;
  int swz = (bid & 7) * 32 + (bid >> 3);   // bijective: 256 % 8 == 0
  int oIdx = swz % 4, pIdx = swz / 4;      // per XCD: pIdx in [8x,8x+8) = batch x
  int oT = oIdx * 192;
  int pG = pIdx * 128;

  int t = threadIdx.x, lane = t & 63, wid = t >> 6;
  int ln = lane & 15, quad = lane >> 4;
  int wm = wid >> 1, wn = wid & 1;

  int lrow = lane >> 2;
  int scg = ((lane & 3) ^ ((lane >> 3) & 3)) * 8;
  bool roleA = wid < 3;
  const u16* Asrc = Wb + (size_t)(oT + wid * 64 + lrow) * CDIM + scg;   // waves 0-2
  const u16* Bsrc = aT + (size_t)(pG + lrow) * CDIM + scg;              // wave 3
  int ldA = wid * 2048;            // u16: wave's 64 A-rows
  int ldB = 6144;                  // B region at 6144

#define STAGEP(bi, kt) do {                                                \
    u16* bb_ = sm + (bi) * 10240;                                          \
    if (roleA) {                                                           \
      const u16* gp_ = Asrc + (kt) * 32;                                   \
      _Pragma("unroll") for (int i_ = 0; i_ < 4; ++i_)                     \
        gload16(gp_ + (size_t)i_ * 16 * CDIM, bb_ + ldA + i_ * 512);       \
    } else {                                                               \
      const u16* gp_ = Bsrc + (kt) * 32;                                   \
      _Pragma("unroll") for (int i_ = 0; i_ < 8; ++i_)                     \
        gload16(gp_ + (size_t)i_ * 16 * CDIM, bb_ + ldB + i_ * 512);       \
    }                                                                      \
  } while (0)

#define DRAINP do {                                                        \
    if (roleA) asm volatile("s_waitcnt vmcnt(4)" ::: "memory");            \
    else asm volatile("s_waitcnt vmcnt(8)" ::: "memory");                  \
  } while (0)

  int slot = (quad ^ ((ln >> 1) & 3)) * 8;
  int rAr = (wm * 96 + ln) * 32;
  int rBr = 6144 + (wn * 64 + ln) * 32;

  v4f acc[6][4] = {};

  STAGEP(0, 0);
  FEN;
  STAGEP(1, 1);
  DRAINP;            // tile 0 resident, tile 1 in flight
  BARQ;

  for (int j = 0; j < NKT; ++j) {
    const u16* sb = sm + (j % 3) * 10240;
    int bi2 = (j + 2) % 3;

    // ---- phase A: issue tile j+2; read A m0-2 + B; 12 MFMA ----
    if (j < NKT - 2) STAGEP(bi2, j + 2);
    bf16x8 af[3], bfr[4];
#pragma unroll
    for (int m = 0; m < 3; ++m)
      af[m] = *(const bf16x8*)&sb[rAr + m * 512 + slot];
#pragma unroll
    for (int n = 0; n < 4; ++n)
      bfr[n] = *(const bf16x8*)&sb[rBr + n * 512 + slot];
    BARQ;
    LGKM0;
    __builtin_amdgcn_sched_barrier(0);
    __builtin_amdgcn_s_setprio(1);
#pragma unroll
    for (int m = 0; m < 3; ++m)
#pragma unroll
      for (int n = 0; n < 4; ++n)
        acc[m][n] = mfma16(af[m], bfr[n], acc[m][n]);
    __builtin_amdgcn_s_setprio(0);
    BARQ;

    // ---- phase B: read A m3-5; counted drain of tile j+1; 12 MFMA ----
    bf16x8 ag[3];
#pragma unroll
    for (int m = 0; m < 3; ++m)
      ag[m] = *(const bf16x8*)&sb[rAr + (m + 3) * 512 + slot];
    if (j < NKT - 2) DRAINP;
    else if (j == NKT - 2) VMC0;
    BARQ;
    LGKM0;
    __builtin_amdgcn_sched_barrier(0);
    __builtin_amdgcn_s_setprio(1);
#pragma unroll
    for (int m = 0; m < 3; ++m)
#pragma unroll
      for (int n = 0; n < 4; ++n)
        acc[m + 3][n] = mfma16(ag[m], bfr[n], acc[m + 3][n]);
    __builtin_amdgcn_s_setprio(0);
    BARQ;
  }

#pragma unroll
  for (int m = 0; m < 6; ++m) {
#pragma unroll
    for (int n = 0; n < 4; ++n) {
      int ro = oT + wm * 96 + m * 16 + quad * 4;
      int cp = pG + wn * 64 + n * 16 + ln;
      int b = cp >> 10, p = cp & 1023;
#pragma unroll
      for (int r = 0; r < 4; ++r)
        out[((size_t)b * CDIM + ro + r) * NSEQ + p] = acc[m][n][r];
    }
  }
#undef STAGEP
#undef DRAINP
}

extern "C" void kernel_launch(void* const* d_in, const int* in_sizes, int n_in,
                              void* d_out, int out_size, void* d_ws, size_t ws_size,
                              hipStream_t stream) {
  const float* x = (const float*)d_in[0];
  const float* w_qkv = (const float*)d_in[1];
  const float* w_proj = (const float*)d_in[2];
  float* out = (float*)d_out;

  char* ws = (char*)d_ws;
  u16* wqkv_bf = (u16*)(ws);
  u16* wproj_bf = (u16*)(ws + 3538944);
  u16* xT = (u16*)(ws + 4718592);
  u16* vbuf = (u16*)(ws + 17301504);
  u16* qkT = (u16*)d_out;
  u16* attnT = xT;

  k_prep<<<dim3(3840), dim3(256), 0, stream>>>(x, w_qkv, w_proj, xT, wqkv_bf, wproj_bf);
  k_gemm_qkv<<<dim3(256), dim3(512), 0, stream>>>(wqkv_bf, xT, qkT, vbuf);
  k_attn<<<dim3(768), dim3(256), 0, stream>>>(qkT, vbuf, attnT);
  k_gemm_proj<<<dim3(256), dim3(256), 0, stream>>>(wproj_bf, attnT, out);
}

// Round 12
// 171.398 us; speedup vs baseline: 1.0375x; 1.0061x over previous
//
#include <hip/hip_runtime.h>

typedef unsigned short u16;
typedef unsigned int u32;
typedef float v4f __attribute__((ext_vector_type(4)));
typedef __bf16 bf16x8 __attribute__((ext_vector_type(8)));

#define BATCH 8
#define CDIM 768
#define NHEAD 12
#define DH 64
#define NSEQ 1024
#define SCL 0.18033688011112042f

__device__ __forceinline__ u16 f2bf(float f) {
  u32 u = __builtin_bit_cast(u32, f);
  u += 0x7fffu + ((u >> 16) & 1u);   // RNE
  return (u16)(u >> 16);
}

__device__ __forceinline__ u16 b16(float f) {
  return (u16)((__builtin_bit_cast(u32, f) + 0x8000u) >> 16);
}

__device__ __forceinline__ u32 pkbf(float hi, float lo) {
  u32 a = __builtin_bit_cast(u32, hi) + 0x8000u;
  u32 b = __builtin_bit_cast(u32, lo) + 0x8000u;
  return __builtin_amdgcn_perm(a, b, 0x07060302u);  // {a[31:16], b[31:16]}
}

__device__ __forceinline__ v4f mfma16(bf16x8 a, bf16x8 b, v4f c) {
  return __builtin_amdgcn_mfma_f32_16x16x32_bf16(a, b, c, 0, 0, 0);
}

__device__ __forceinline__ void gload16(const u16* g, u16* l) {
  __builtin_amdgcn_global_load_lds(
      (const __attribute__((address_space(1))) void*)g,
      (__attribute__((address_space(3))) void*)l, 16, 0, 0);
}

#define BARQ asm volatile("s_barrier" ::: "memory")
#define LGKM0 asm volatile("s_waitcnt lgkmcnt(0)" ::: "memory")
#define VMC0 asm volatile("s_waitcnt vmcnt(0)" ::: "memory")
#define FEN asm volatile("" ::: "memory")

// ------------- kernel: fused prep --------------------------------------
__global__ __launch_bounds__(256) void k_prep(const float* __restrict__ x,
                                              const float* __restrict__ wq,
                                              const float* __restrict__ wp,
                                              u16* __restrict__ xT,
                                              u16* __restrict__ wqb,
                                              u16* __restrict__ wpb) {
  __shared__ u16 Ts[64][72];
  int bid = blockIdx.x;
  int t = threadIdx.x;
  if (bid < 2304) {
    bool isQ = bid < 1728;
    const float* s = isQ ? wq : wp;
    u16* d = isQ ? wqb : wpb;
    int i = (isQ ? bid : bid - 1728) * 256 + t;
    float4 v = ((const float4*)s)[i];
    u32 lo = (u32)f2bf(v.x) | ((u32)f2bf(v.y) << 16);
    u32 hi = (u32)f2bf(v.z) | ((u32)f2bf(v.w) << 16);
    ((uint2*)d)[i] = uint2{lo, hi};
    return;
  }
  int id = bid - 2304;
  int p0 = (id & 15) * 64; id >>= 4;
  int c0 = (id % 12) * 64; int b = id / 12;
  int cr = t >> 4;
  int p4 = (t & 15) * 4;
  const float* src = x + ((size_t)b * CDIM + c0) * NSEQ + p0;
#pragma unroll
  for (int i = 0; i < 4; ++i) {
    int c = cr + i * 16;
    float4 v = *(const float4*)&src[(size_t)c * NSEQ + p4];
    Ts[p4 + 0][c] = f2bf(v.x);
    Ts[p4 + 1][c] = f2bf(v.y);
    Ts[p4 + 2][c] = f2bf(v.z);
    Ts[p4 + 3][c] = f2bf(v.w);
  }
  __syncthreads();
  int p = t >> 2;
  int cq = t & 3;
  u16* dst = xT + ((size_t)b * NSEQ + p0 + p) * CDIM + c0;
#pragma unroll
  for (int j = 0; j < 2; ++j) {
    int ch = cq + j * 4;
    *(int4*)&dst[ch * 8] = *(const int4*)&Ts[p][ch * 8];
  }
}

// ------------- kernel: QKV GEMM, 288x256 tile, BK=64 dbuf 4-phase -------
// Grid 256 (balanced, R8-proven). 512 thr / 8 waves (2M x 4N), wave-tile
// 144x64, acc[9][4]. LDS 2 bufs x (A 288x64 @0 + B 256x64 @18432) =
// 136 KB -> 1 blk/CU. 4 phases/K-tile (R5's measured 3.4 TF/CU schedule):
// p0{rd A m0-4 k0 + B k0; stage half0(j+1)} p1{rd A m5-8 k0; stage half1}
// p2{rd k1 frags} p3{rd; vmcnt(0) -- all j+1 loads issued by p1, >=2
// phases (~1200cy) earlier, so the drain is a no-wait}. 2 barriers/phase.
// Staging swizzle (attn-proven): 8 rows x 8 chunks/gload16, slot (l&7)
// sources global chunk (l&7)^((l>>3)&7); frag slots (quad^(ln&7)) and
// ((4+quad)^(ln&7)). k-order ascending 32-chunks -> absmax bit-identical.
__global__ __launch_bounds__(512, 2) void k_gemm_qkv(const u16* __restrict__ Wb,
                                                     const u16* __restrict__ xT,
                                                     u16* __restrict__ qkT,
                                                     u16* __restrict__ vbuf) {
  __shared__ u16 sm[2 * 34816];   // 136 KB
  int bid = blockIdx.x;
  int swz = (bid & 7) * 32 + (bid >> 3);   // bijective: 256 % 8 == 0
  int oIdx = swz % 8, pIdx = swz / 8;      // per XCD: pIdx in [4x,4x+4) = batch x
  int oT = oIdx * 288;
  int pG = pIdx * 256;

  int t = threadIdx.x, lane = t & 63, wid = t >> 6;
  int ln = lane & 15, quad = lane >> 4;
  int wm = wid >> 2, wn = wid & 3;

  int sr8 = lane >> 3;
  int sch = ((lane & 7) ^ sr8) * 8;
  bool roleA = wid < 6;
  int w6 = wid - 6;
  const u16* Asrc = Wb + (size_t)(oT + wid * 48 + sr8) * CDIM + sch;        // waves 0-5
  const u16* Bsrc = xT + (size_t)(pG + (w6 < 0 ? 0 : w6) * 128 + sr8) * CDIM + sch;
  int ldA = wid * 3072;                    // (wid*48)*64 u16
  int ldB = 18432 + (w6 < 0 ? 0 : w6) * 8192;

// stage half h (0/1) of K-tile kt into buffer bi
#define STGH(bi, kt, h) do {                                               \
    u16* bb_ = sm + (bi) * 34816;                                          \
    if (roleA) {                                                           \
      const u16* gp_ = Asrc + (size_t)(kt) * 64;                           \
      _Pragma("unroll") for (int i_ = 3 * (h); i_ < 3 * (h) + 3; ++i_)     \
        gload16(gp_ + (size_t)i_ * 8 * CDIM, bb_ + ldA + i_ * 512);        \
    } else {                                                               \
      const u16* gp_ = Bsrc + (size_t)(kt) * 64;                           \
      _Pragma("unroll") for (int i_ = 8 * (h); i_ < 8 * (h) + 8; ++i_)     \
        gload16(gp_ + (size_t)i_ * 8 * CDIM, bb_ + ldB + i_ * 512);        \
    }                                                                      \
  } while (0)

  int slot0 = (quad ^ (ln & 7)) * 8;        // k-chunks 0-3 (k 0..31)
  int slot1 = ((4 + quad) ^ (ln & 7)) * 8;  // k-chunks 4-7 (k 32..63)
  int rAr = (wm * 144 + ln) * 64;
  int rBr = 18432 + (wn * 64 + ln) * 64;

  v4f acc[9][4] = {};
  bf16x8 af[5], bfr[4];

  // ---- prologue: tile 0 -> buf 0, drain ----
  STGH(0, 0, 0);
  STGH(0, 0, 1);
  VMC0;
  BARQ;

  for (int j = 0; j < 12; ++j) {
    const u16* sb = sm + (j & 1) * 34816;
    int nb = (j & 1) ^ 1;
    bool nl = j < 11;

    // ---- p0: A m0-4 k0 + B k0; stage half0(j+1); 20 MFMA ----
#pragma unroll
    for (int m = 0; m < 5; ++m)
      af[m] = *(const bf16x8*)&sb[rAr + m * 1024 + slot0];
#pragma unroll
    for (int n = 0; n < 4; ++n)
      bfr[n] = *(const bf16x8*)&sb[rBr + n * 1024 + slot0];
    if (nl) STGH(nb, j + 1, 0);
    BARQ;
    LGKM0;
    __builtin_amdgcn_sched_barrier(0);
    __builtin_amdgcn_s_setprio(1);
#pragma unroll
    for (int m = 0; m < 5; ++m)
#pragma unroll
      for (int n = 0; n < 4; ++n)
        acc[m][n] = mfma16(af[m], bfr[n], acc[m][n]);
    __builtin_amdgcn_s_setprio(0);
    BARQ;

    // ---- p1: A m5-8 k0; stage half1(j+1); 16 MFMA ----
#pragma unroll
    for (int m = 0; m < 4; ++m)
      af[m] = *(const bf16x8*)&sb[rAr + (m + 5) * 1024 + slot0];
    if (nl) STGH(nb, j + 1, 1);
    BARQ;
    LGKM0;
    __builtin_amdgcn_sched_barrier(0);
    __builtin_amdgcn_s_setprio(1);
#pragma unroll
    for (int m = 0; m < 4; ++m)
#pragma unroll
      for (int n = 0; n < 4; ++n)
        acc[m + 5][n] = mfma16(af[m], bfr[n], acc[m + 5][n]);
    __builtin_amdgcn_s_setprio(0);
    BARQ;

    // ---- p2: A m0-4 k1 + B k1; 20 MFMA ----
#pragma unroll
    for (int m = 0; m < 5; ++m)
      af[m] = *(const bf16x8*)&sb[rAr + m * 1024 + slot1];
#pragma unroll
    for (int n = 0; n < 4; ++n)
      bfr[n] = *(const bf16x8*)&sb[rBr + n * 1024 + slot1];
    BARQ;
    LGKM0;
    __builtin_amdgcn_sched_barrier(0);
    __builtin_amdgcn_s_setprio(1);
#pragma unroll
    for (int m = 0; m < 5; ++m)
#pragma unroll
      for (int n = 0; n < 4; ++n)
        acc[m][n] = mfma16(af[m], bfr[n], acc[m][n]);
    __builtin_amdgcn_s_setprio(0);
    BARQ;

    // ---- p3: A m5-8 k1; drain tile j+1 (issued >=2 phases ago); 16 MFMA --
#pragma unroll
    for (int m = 0; m < 4; ++m)
      af[m] = *(const bf16x8*)&sb[rAr + (m + 5) * 1024 + slot1];
    if (nl) VMC0;
    BARQ;
    LGKM0;
    __builtin_amdgcn_sched_barrier(0);
    __builtin_amdgcn_s_setprio(1);
#pragma unroll
    for (int m = 0; m < 4; ++m)
#pragma unroll
      for (int n = 0; n < 4; ++n)
        acc[m + 5][n] = mfma16(af[m], bfr[n], acc[m + 5][n]);
    __builtin_amdgcn_s_setprio(0);
    BARQ;
  }

  // ---- epilogue: ro < 1536 -> qkT (transposed), else -> vbuf ----
#pragma unroll
  for (int m = 0; m < 9; ++m) {
#pragma unroll
    for (int n = 0; n < 4; ++n) {
      int ro = oT + wm * 144 + m * 16 + quad * 4;
      int cp = pG + wn * 64 + n * 16 + ln;
      int b = cp >> 10, p = cp & 1023;
      if (ro < 2 * CDIM) {
        u32 lo = (u32)f2bf(acc[m][n][0]) | ((u32)f2bf(acc[m][n][1]) << 16);
        u32 hi = (u32)f2bf(acc[m][n][2]) | ((u32)f2bf(acc[m][n][3]) << 16);
        *(uint2*)&qkT[((size_t)b * NSEQ + p) * 1536 + ro] = uint2{lo, hi};
      } else {
#pragma unroll
        for (int r = 0; r < 4; ++r)
          vbuf[((size_t)b * CDIM + (ro - 2 * CDIM + r)) * NSEQ + p] =
              f2bf(acc[m][n][r]);
      }
    }
  }
#undef STGH
}

// ------------- kernel: flash attention (R11 T15, verbatim) --------------
__global__ __launch_bounds__(256) void k_attn(const u16* __restrict__ qkT,
                                              const u16* __restrict__ vbuf,
                                              u16* __restrict__ attnT) {
  int id = blockIdx.x;
  int b = id & 7;
  int j = id >> 3;
  int h = j % 12;
  int nt0 = (j / 12) * 128;

  int t = threadIdx.x, lane = t & 63, wid = t >> 6;
  int ln = lane & 15, quad = lane >> 4;
  int nbase = nt0 + wid * 32;

  __shared__ u16 Ks[2][64 * 64];
  __shared__ u16 Vs[2][64 * 64];
  __shared__ u16 Pa[4][32 * 64];   // [wave][n][m-swizzled], 4 KB/wave
  u16* myP = Pa[wid];

  const u16* qbase = qkT + ((size_t)b * NSEQ + nbase) * 1536 + h * DH;
  bf16x8 aq[2][2];
#pragma unroll
  for (int mt = 0; mt < 2; ++mt)
#pragma unroll
    for (int ks = 0; ks < 2; ++ks)
      aq[mt][ks] = *(const bf16x8*)&qbase[(size_t)(mt * 16 + ln) * 1536 + ks * 32 + quad * 8];

  bf16x8 ones;
#pragma unroll
  for (int i = 0; i < 8; ++i) ones[i] = __builtin_bit_cast(__bf16, (u16)0x3F80);

  v4f oacc[2][4] = {};
  v4f lacc[2] = {};

  int sr8 = lane >> 3;
  int sch = ((lane & 7) ^ sr8) * 8;
  const u16* kg0 = qkT + ((size_t)b * NSEQ + wid * 16 + sr8) * 1536 + CDIM + h * DH + sch;
  const u16* vg0 = vbuf + ((size_t)b * CDIM + h * DH + wid * 16 + sr8) * NSEQ + sch;
  int sK = wid * 1024;   // wave's 16-row LDS slab base (u16)

  int sw0 = (quad ^ (ln & 7)) * 8;
  int sw1 = ((4 + quad) ^ (ln & 7)) * 8;
  int e7 = ln & 7;

#define STAGEK(kb, s_) do { size_t ko_ = (size_t)(s_) * 64 * 1536;          \
    gload16(kg0 + ko_, &Ks[kb][sK]);                                        \
    gload16(kg0 + ko_ + (size_t)8 * 1536, &Ks[kb][sK + 512]); } while (0)
#define STAGEV(vb, s_) do { int vo_ = (s_) * 64;                            \
    gload16(vg0 + vo_, &Vs[vb][sK]);                                        \
    gload16(vg0 + vo_ + 8 * NSEQ, &Vs[vb][sK + 512]); } while (0)

#define QKEXP(kb) do {                                                      \
    _Pragma("unroll") for (int ct = 0; ct < 4; ++ct) {                      \
      bf16x8 kf0 = *(const bf16x8*)&Ks[kb][(ct * 16 + ln) * 64 + sw0];      \
      bf16x8 kf1 = *(const bf16x8*)&Ks[kb][(ct * 16 + ln) * 64 + sw1];      \
      _Pragma("unroll") for (int mt = 0; mt < 2; ++mt) {                    \
        v4f sc = {};                                                        \
        sc = mfma16(kf0, aq[mt][0], sc);                                    \
        sc = mfma16(kf1, aq[mt][1], sc);                                    \
        float p0 = __builtin_amdgcn_exp2f(sc[0] * SCL);                     \
        float p1 = __builtin_amdgcn_exp2f(sc[1] * SCL);                     \
        float p2 = __builtin_amdgcn_exp2f(sc[2] * SCL);                     \
        float p3 = __builtin_amdgcn_exp2f(sc[3] * SCL);                     \
        int woff = (mt * 16 + ln) * 64 +                                    \
                   (((2 * ct + (quad >> 1)) ^ e7) * 8 + (quad & 1) * 4);    \
        *(uint2*)&myP[woff] = uint2{pkbf(p1, p0), pkbf(p3, p2)};            \
      }                                                                     \
    }                                                                       \
  } while (0)

#define READAP(ap) do {                                                     \
    _Pragma("unroll") for (int mt = 0; mt < 2; ++mt)                        \
      _Pragma("unroll") for (int ks = 0; ks < 2; ++ks)                      \
        ap[mt][ks] = *(const bf16x8*)&myP[(mt * 16 + ln) * 64 +             \
                                          ((ks * 4 + quad) ^ e7) * 8];      \
  } while (0)

#define PVSTEP(vb, ap) do {                                                 \
    __builtin_amdgcn_s_setprio(1);                                          \
    _Pragma("unroll") for (int mt = 0; mt < 2; ++mt) {                      \
      lacc[mt] = mfma16(ap[mt][0], ones, lacc[mt]);                         \
      lacc[mt] = mfma16(ap[mt][1], ones, lacc[mt]);                         \
    }                                                                       \
    __builtin_amdgcn_s_setprio(0);                                          \
    _Pragma("unroll") for (int nt = 0; nt < 4; ++nt) {                      \
      bf16x8 vf0 = *(const bf16x8*)&Vs[vb][(nt * 16 + ln) * 64 + sw0];      \
      bf16x8 vf1 = *(const bf16x8*)&Vs[vb][(nt * 16 + ln) * 64 + sw1];      \
      __builtin_amdgcn_s_setprio(1);                                        \
      _Pragma("unroll") for (int mt = 0; mt < 2; ++mt) {                    \
        oacc[mt][nt] = mfma16(ap[mt][0], vf0, oacc[mt][nt]);                \
        oacc[mt][nt] = mfma16(ap[mt][1], vf1, oacc[mt][nt]);                \
      }                                                                     \
      __builtin_amdgcn_s_setprio(0);                                        \
    }                                                                       \
  } while (0)

  bf16x8 apA[2][2], apB[2][2];

  // ---- prologue: slab 0 resident; P(0) computed; K(1) in flight ----
  STAGEK(0, 0);
  STAGEV(0, 0);
  __syncthreads();
  QKEXP(0);
  STAGEK(1, 1);
  READAP(apA);

#pragma unroll 1
  for (int s = 0; s < 16; s += 2) {
    // ---- even half: QK(s+1) | PV(s) ----
    __syncthreads();                       // drains K(s+1), V(s)
    if (s < 14) STAGEK(0, s + 2);          // Kbuf0: K(s) dead
    STAGEV(1, s + 1);                      // Vbuf1: V(s-1) dead
    QKEXP(1);                              // K(s+1) from Kbuf1
    PVSTEP(0, apA);                        // V(s) from Vbuf0, P(s)
    READAP(apB);                           // P(s+1), gap filled by PV
    // ---- odd half: QK(s+2) | PV(s+1) ----
    __syncthreads();                       // drains K(s+2), V(s+1)
    if (s < 13) STAGEK(1, s + 3);          // Kbuf1: K(s+1) dead
    if (s < 14) {
      STAGEV(0, s + 2);                    // Vbuf0: V(s) dead
      QKEXP(0);                            // K(s+2) from Kbuf0
    }
    PVSTEP(1, apB);                        // V(s+1) from Vbuf1, P(s+1)
    if (s < 14) READAP(apA);               // P(s+2)
  }

#undef STAGEK
#undef STAGEV
#undef QKEXP
#undef READAP
#undef PVSTEP

#pragma unroll
  for (int mt = 0; mt < 2; ++mt) {
#pragma unroll
    for (int r = 0; r < 4; ++r) {
      float inv = 1.0f / lacc[mt][r];
      int n = nbase + mt * 16 + quad * 4 + r;
      u16* dst = attnT + ((size_t)b * NSEQ + n) * CDIM + h * DH;
#pragma unroll
      for (int nt = 0; nt < 4; ++nt)
        dst[nt * 16 + ln] = b16(oacc[mt][nt][r] * inv);
    }
  }
}

// ------------- kernel: proj GEMM, 192x128 tile, 256 blocks (R10 verbatim)
__global__ __launch_bounds__(256, 2) void k_gemm_proj(const u16* __restrict__ Wb,
                                                      const u16* __restrict__ aT,
                                                      float* __restrict__ out) {
  __shared__ u16 sm[3 * 10240];   // 3 x (A 192x32 + B 128x32) = 60 KB
  int bid = blockIdx.x;
  int swz = (bid & 7) * 32 + (bid >> 3);   // bijective: 256 % 8 == 0
  int oIdx = swz % 4, pIdx = swz / 4;      // per XCD: pIdx in [8x,8x+8) = batch x
  int oT = oIdx * 192;
  int pG = pIdx * 128;

  int t = threadIdx.x, lane = t & 63, wid = t >> 6;
  int ln = lane & 15, quad = lane >> 4;
  int wm = wid >> 1, wn = wid & 1;

  int lrow = lane >> 2;
  int scg = ((lane & 3) ^ ((lane >> 3) & 3)) * 8;
  bool roleA = wid < 3;
  const u16* Asrc = Wb + (size_t)(oT + wid * 64 + lrow) * CDIM + scg;   // waves 0-2
  const u16* Bsrc = aT + (size_t)(pG + lrow) * CDIM + scg;              // wave 3
  int ldA = wid * 2048;            // u16: wave's 64 A-rows
  int ldB = 6144;                  // B region at 6144

#define STAGEP(bi, kt) do {                                                \
    u16* bb_ = sm + (bi) * 10240;                                          \
    if (roleA) {                                                           \
      const u16* gp_ = Asrc + (kt) * 32;                                   \
      _Pragma("unroll") for (int i_ = 0; i_ < 4; ++i_)                     \
        gload16(gp_ + (size_t)i_ * 16 * CDIM, bb_ + ldA + i_ * 512);       \
    } else {                                                               \
      const u16* gp_ = Bsrc + (kt) * 32;                                   \
      _Pragma("unroll") for (int i_ = 0; i_ < 8; ++i_)                     \
        gload16(gp_ + (size_t)i_ * 16 * CDIM, bb_ + ldB + i_ * 512);       \
    }                                                                      \
  } while (0)

#define DRAINP do {                                                        \
    if (roleA) asm volatile("s_waitcnt vmcnt(4)" ::: "memory");            \
    else asm volatile("s_waitcnt vmcnt(8)" ::: "memory");                  \
  } while (0)

  int slot = (quad ^ ((ln >> 1) & 3)) * 8;
  int rAr = (wm * 96 + ln) * 32;
  int rBr = 6144 + (wn * 64 + ln) * 32;

  v4f acc[6][4] = {};

  STAGEP(0, 0);
  FEN;
  STAGEP(1, 1);
  DRAINP;            // tile 0 resident, tile 1 in flight
  BARQ;

  for (int j = 0; j < 24; ++j) {
    const u16* sb = sm + (j % 3) * 10240;
    int bi2 = (j + 2) % 3;

    // ---- phase A: issue tile j+2; read A m0-2 + B; 12 MFMA ----
    if (j < 22) STAGEP(bi2, j + 2);
    bf16x8 af[3], bfr[4];
#pragma unroll
    for (int m = 0; m < 3; ++m)
      af[m] = *(const bf16x8*)&sb[rAr + m * 512 + slot];
#pragma unroll
    for (int n = 0; n < 4; ++n)
      bfr[n] = *(const bf16x8*)&sb[rBr + n * 512 + slot];
    BARQ;
    LGKM0;
    __builtin_amdgcn_sched_barrier(0);
    __builtin_amdgcn_s_setprio(1);
#pragma unroll
    for (int m = 0; m < 3; ++m)
#pragma unroll
      for (int n = 0; n < 4; ++n)
        acc[m][n] = mfma16(af[m], bfr[n], acc[m][n]);
    __builtin_amdgcn_s_setprio(0);
    BARQ;

    // ---- phase B: read A m3-5; counted drain of tile j+1; 12 MFMA ----
    bf16x8 ag[3];
#pragma unroll
    for (int m = 0; m < 3; ++m)
      ag[m] = *(const bf16x8*)&sb[rAr + (m + 3) * 512 + slot];
    if (j < 22) DRAINP;
    else if (j == 22) VMC0;
    BARQ;
    LGKM0;
    __builtin_amdgcn_sched_barrier(0);
    __builtin_amdgcn_s_setprio(1);
#pragma unroll
    for (int m = 0; m < 3; ++m)
#pragma unroll
      for (int n = 0; n < 4; ++n)
        acc[m + 3][n] = mfma16(ag[m], bfr[n], acc[m + 3][n]);
    __builtin_amdgcn_s_setprio(0);
    BARQ;
  }

#pragma unroll
  for (int m = 0; m < 6; ++m) {
#pragma unroll
    for (int n = 0; n < 4; ++n) {
      int ro = oT + wm * 96 + m * 16 + quad * 4;
      int cp = pG + wn * 64 + n * 16 + ln;
      int b = cp >> 10, p = cp & 1023;
#pragma unroll
      for (int r = 0; r < 4; ++r)
        out[((size_t)b * CDIM + ro + r) * NSEQ + p] = acc[m][n][r];
    }
  }
#undef STAGEP
#undef DRAINP
}

extern "C" void kernel_launch(void* const* d_in, const int* in_sizes, int n_in,
                              void* d_out, int out_size, void* d_ws, size_t ws_size,
                              hipStream_t stream) {
  const float* x = (const float*)d_in[0];
  const float* w_qkv = (const float*)d_in[1];
  const float* w_proj = (const float*)d_in[2];
  float* out = (float*)d_out;

  char* ws = (char*)d_ws;
  u16* wqkv_bf = (u16*)(ws);
  u16* wproj_bf = (u16*)(ws + 3538944);
  u16* xT = (u16*)(ws + 4718592);
  u16* vbuf = (u16*)(ws + 17301504);
  u16* qkT = (u16*)d_out;
  u16* attnT = xT;

  k_prep<<<dim3(3840), dim3(256), 0, stream>>>(x, w_qkv, w_proj, xT, wqkv_bf, wproj_bf);
  k_gemm_qkv<<<dim3(256), dim3(512), 0, stream>>>(wqkv_bf, xT, qkT, vbuf);
  k_attn<<<dim3(768), dim3(256), 0, stream>>>(qkT, vbuf, attnT);
  k_gemm_proj<<<dim3(256), dim3(256), 0, stream>>>(wproj_bf, attnT, out);
}